// Round 15
// baseline (136.462 us; speedup 1.0000x reference)
//
#include <hip/hip_runtime.h>
#include <math.h>

#define NBINS   64
#define GROUPS  16
#define HIDDEN  128
#define EPSF    1e-6f

// B=2, C=16, H=W=1024; 32 images of 1M floats; 32x32 tiles of 32x32 elems.
#define IMG_ELEMS   (1024*1024)
#define F4_PER_ROW  256          // 1024 cols / 4
#define NIMG        32           // B*C

typedef float nfloat4 __attribute__((ext_vector_type(4)));  // builtin-compatible

// ---------------------------------------------------------------------------
// Kernel 1: per image-row-chunk (32 rows): min/max partials + 32 tile sums.
// grid = NIMG*32 blocks, 256 threads. (R9-proven, unchanged.)
// ---------------------------------------------------------------------------
__global__ __launch_bounds__(256) void k_stats(
        const float* __restrict__ x,
        float* __restrict__ blocksum,   // [NIMG][1024] tile sums
        float* __restrict__ pmin,       // [NIMG*32]
        float* __restrict__ pmax)       // [NIMG*32]
{
    const int bid = blockIdx.x;
    const int bc  = bid >> 5;   // image
    const int i   = bid & 31;   // tile row
    const int t   = threadIdx.x;
    const int lane = t & 63;
    const int wave = t >> 6;

    const float4* xin = (const float4*)(x + (size_t)bc * IMG_ELEMS);
    const int rowbase = (i * 32) * F4_PER_ROW;

    float s = 0.f, mn = INFINITY, mx = -INFINITY;
    #pragma unroll 4
    for (int r = 0; r < 32; ++r) {
        float4 v = xin[rowbase + r * F4_PER_ROW + t];
        s += (v.x + v.y) + (v.z + v.w);
        mn = fminf(mn, fminf(fminf(v.x, v.y), fminf(v.z, v.w)));
        mx = fmaxf(mx, fmaxf(fmaxf(v.x, v.y), fmaxf(v.z, v.w)));
    }

    s += __shfl_xor(s, 4, 64);
    s += __shfl_xor(s, 2, 64);
    s += __shfl_xor(s, 1, 64);
    if ((t & 7) == 0)
        blocksum[bc * 1024 + i * 32 + (t >> 3)] = s;

    #pragma unroll
    for (int st = 32; st > 0; st >>= 1) {
        mn = fminf(mn, __shfl_xor(mn, st, 64));
        mx = fmaxf(mx, __shfl_xor(mx, st, 64));
    }
    __shared__ float wmn[4], wmx[4];
    if (lane == 0) { wmn[wave] = mn; wmx[wave] = mx; }
    __syncthreads();
    if (t == 0) {
        pmin[bid] = fminf(fminf(wmn[0], wmn[1]), fminf(wmn[2], wmn[3]));
        pmax[bid] = fmaxf(fmaxf(wmx[0], wmx[1]), fmaxf(wmx[2], wmx[3]));
    }
}

// ---------------------------------------------------------------------------
// Kernel 2: fused per-image min/max finalize + ballot histogram -> scaled
// cdf. grid = 32 blocks, 256 threads. (R9-proven, unchanged.)
// ---------------------------------------------------------------------------
__global__ __launch_bounds__(256) void k_hist(
        const float* __restrict__ pmin, const float* __restrict__ pmax,
        const float* __restrict__ blocksum,
        float* __restrict__ gmin, float* __restrict__ gmax,
        float* __restrict__ pcdf)       // [2][16][64]
{
    const int bc   = blockIdx.x;
    const int t    = threadIdx.x;
    const int lane = t & 63;
    const int wave = t >> 6;

    __shared__ float s_mn, s_inv;
    if (wave == 0) {
        float mn = (lane < 32) ? pmin[bc * 32 + lane] : INFINITY;
        float mx = (lane < 32) ? pmax[bc * 32 + lane] : -INFINITY;
        #pragma unroll
        for (int st = 32; st > 0; st >>= 1) {
            mn = fminf(mn, __shfl_xor(mn, st, 64));
            mx = fmaxf(mx, __shfl_xor(mx, st, 64));
        }
        if (lane == 0) {
            gmin[bc] = mn; gmax[bc] = mx;
            s_mn = mn; s_inv = 1.0f / (mx - mn + EPSF);
        }
    }
    __syncthreads();
    const float mnv = s_mn;
    const float inv = s_inv;

    int idx0, idx1, idx2, idx3;
    {
        const float* bs = blocksum + bc * 1024;
        #define MKIDX(D, IT) { \
            float bmean = bs[t + (IT)*256] * (1.0f / 1024.0f); \
            float xs = (bmean - mnv) * inv; \
            int id = (int)rintf(xs * 63.0f); \
            D = max(0, min(id, 63)); }
        MKIDX(idx0, 0) MKIDX(idx1, 1) MKIDX(idx2, 2) MKIDX(idx3, 3)
        #undef MKIDX
    }

    int cnt = 0;
    #pragma unroll 1
    for (int b = 0; b < NBINS; ++b) {
        int p = __popcll(__ballot(idx0 == b)) + __popcll(__ballot(idx1 == b))
              + __popcll(__ballot(idx2 == b)) + __popcll(__ballot(idx3 == b));
        cnt += (lane == b) ? p : 0;
    }

    __shared__ int whist[4][NBINS];
    whist[wave][lane] = cnt;
    __syncthreads();

    if (t < NBINS) {
        int h = whist[0][t] + whist[1][t] + whist[2][t] + whist[3][t];
        #pragma unroll
        for (int d = 1; d < 64; d <<= 1) {
            int v = __shfl_up(h, d, 64);
            if (t >= d) h += v;
        }
        pcdf[bc * NBINS + t] = (float)h * (0.5f / (1024.0f + EPSF));
    }
}

// ---------------------------------------------------------------------------
// Kernel 3: MEGA apply. grid = 512 blocks x 1024 threads (2 blocks/CU).
// Each block REDUNDANTLY computes conv1+conv2 (all 128 ch, LDS weights in 4
// chunks, shuffle-conv2 race-free) into LDS, conv3 for its own group via
// 16-wave partials, softplus + shuffle-scan cumsum + ramp -> lut_s; then
// remaps 4 image-parts (16 float4/thread) with nontemporal stores.
// Redundant compute replaces a dispatch boundary + k_conv12 (R10-R13:
// cross-block sync costs 10-50x its model on this chip; dispatches ~6us).
// LDS ~51KB -> 2 blocks/CU fit in 160KB.
// ---------------------------------------------------------------------------
__global__ __launch_bounds__(1024, 2) void k_apply(
        const float* __restrict__ x,
        const float* __restrict__ gmin, const float* __restrict__ gmax,
        const float* __restrict__ pcdf,
        const float* __restrict__ w1, const float* __restrict__ b1,
        const float* __restrict__ w2, const float* __restrict__ b2,
        const float* __restrict__ w3, const float* __restrict__ b3,
        const float* __restrict__ alpha,
        float* __restrict__ out)
{
    const int bid   = blockIdx.x;
    const int img   = bid >> 4;        // 16 blocks per image
    const int part  = bid & 15;        // each covers 1/16 of the image
    const int c     = img & 15;        // channel == group (C/G == 1)
    const int t     = threadIdx.x;
    const int lane  = t & 63;
    const int wave  = t >> 6;          // 0..15

    __shared__ float dcdf[GROUPS][NBINS];        // 4KB
    __shared__ float h2s[HIDDEN][NBINS];         // 32KB
    __shared__ float wchunk[32 * 80];            // 10KB
    __shared__ float w2s[32][5];
    __shared__ float b1s[32], b2s[32];
    __shared__ float partial[16][NBINS];         // 4KB
    __shared__ float lut_s[NBINS];

    // dcdf = mean over b of the pre-scaled cdf halves
    if (t < GROUPS * NBINS)
        ((float*)dcdf)[t] = pcdf[t] + pcdf[GROUPS * NBINS + t];
    __syncthreads();

    // ---- conv1 (16->128, 5 taps) + shuffle conv2, 4 chunks of 32 ch -------
    const int k = lane;
    for (int cc = 0; cc < 4; ++cc) {
        for (int o = t; o < 32 * 80; o += 1024) {
            const int ocl = o / 80, rem = o % 80;
            const int ic = rem / 5, tap = rem % 5;
            wchunk[o] = w1[((cc * 32 + ocl) * GROUPS + ic) * 25 + 10 + tap];
        }
        if (t < 160)      w2s[t / 5][t % 5] = w2[(cc * 32 + t / 5) * 25 + 10 + t % 5];
        else if (t < 192) b1s[t - 160] = b1[cc * 32 + t - 160];
        else if (t < 224) b2s[t - 192] = b2[cc * 32 + t - 192];
        __syncthreads();

        #pragma unroll 2
        for (int r = 0; r < 2; ++r) {
            const int ocl = wave * 2 + r;         // 0..31, wave-uniform
            const int oc  = cc * 32 + ocl;
            float acc = b1s[ocl];
            const float* wp = wchunk + ocl * 80;
            for (int ic = 0; ic < GROUPS; ++ic) {
                #pragma unroll
                for (int tap = 0; tap < 5; ++tap) {
                    const int kk = k - 2 + tap;
                    if (kk >= 0 && kk < NBINS)
                        acc += wp[ic * 5 + tap] * dcdf[ic][kk];
                }
            }
            const float c1 = fmaxf(acc, 0.f);
            const float m2v = __shfl_up(c1, 2, 64);
            const float m1v = __shfl_up(c1, 1, 64);
            const float p1v = __shfl_down(c1, 1, 64);
            const float p2v = __shfl_down(c1, 2, 64);
            float a = b2s[ocl];
            a += w2s[ocl][0] * ((k >= 2) ? m2v : 0.f);
            a += w2s[ocl][1] * ((k >= 1) ? m1v : 0.f);
            a += w2s[ocl][2] * c1;
            a += w2s[ocl][3] * ((k <= 62) ? p1v : 0.f);
            a += w2s[ocl][4] * ((k <= 61) ? p2v : 0.f);
            h2s[oc][k] = fmaxf(a, 0.f);
        }
        __syncthreads();   // wchunk reuse next chunk
    }

    // ---- conv3 for this block's group: wave w covers h = w*8..w*8+7 -------
    {
        float pa = 0.f;
        const float* w3p = w3 + c * HIDDEN + wave * 8;   // wave-uniform
        #pragma unroll
        for (int j = 0; j < 8; ++j)
            pa += w3p[j] * h2s[wave * 8 + j][k];
        partial[wave][k] = pa;
    }
    __syncthreads();
    if (wave == 0) {
        float acc = b3[c];
        #pragma unroll
        for (int w = 0; w < 16; ++w) acc += partial[w][k];
        float d = fmaxf(acc, 0.f) + log1pf(expf(-fabsf(acc)));  // softplus
        #pragma unroll
        for (int dd = 1; dd < 64; dd <<= 1) {
            float v = __shfl_up(d, dd, 64);
            if (k >= dd) d += v;
        }
        const float tot = __shfl(d, 63, 64);
        lut_s[k] = d / (tot + EPSF) + (float)k * (1.0f / 63.0f);
    }
    __syncthreads();

    // ---- remap 1/16 of the image: 16384 float4 / 1024 threads ------------
    const float mnv = gmin[img];
    const float mxv = gmax[img];
    const float r   = mxv - mnv;
    const float inv = 1.0f / (r + EPSF);
    const float aa  = 1.0f / (1.0f + expf(-alpha[0]));

    const size_t base4 = (size_t)img * (IMG_ELEMS / 4) + (size_t)part * 16384;
    const float4* xin = (const float4*)x;
    nfloat4* o4 = (nfloat4*)out;

    #pragma unroll 2
    for (int it = 0; it < 16; ++it) {
        const size_t f = base4 + (size_t)t + (size_t)it * 1024;
        float4 v = xin[f];
        nfloat4 w;
        #define REMAP(DST, SRC) { \
            float x01 = (SRC - mnv) * inv; \
            float pos = x01 * 63.0f; \
            int il = max(0, min((int)floorf(pos), 63)); \
            int ih = min(il + 1, 63); \
            float wt = pos - (float)il; \
            float vlo = lut_s[il], vhi = lut_s[ih]; \
            DST = (aa * fmaf(wt, vhi - vlo, vlo) + (1.0f - aa) * x01) * r + mnv; }
        REMAP(w.x, v.x) REMAP(w.y, v.y) REMAP(w.z, v.z) REMAP(w.w, v.w)
        #undef REMAP
        __builtin_nontemporal_store(w, &o4[f]);
    }
}

// ---------------------------------------------------------------------------
extern "C" void kernel_launch(void* const* d_in, const int* in_sizes, int n_in,
                              void* d_out, int out_size, void* d_ws, size_t ws_size,
                              hipStream_t stream)
{
    const float* x     = (const float*)d_in[0];
    const float* w1    = (const float*)d_in[1];
    const float* b1    = (const float*)d_in[2];
    const float* w2    = (const float*)d_in[3];
    const float* b2    = (const float*)d_in[4];
    const float* w3    = (const float*)d_in[5];
    const float* b3    = (const float*)d_in[6];
    const float* alpha = (const float*)d_in[7];
    float* out = (float*)d_out;

    float* ws = (float*)d_ws;
    float* blocksum = ws;            // 32768
    float* pmin     = ws + 32768;    // 1024
    float* pmax     = ws + 33792;    // 1024
    float* gmin     = ws + 34816;    // 32
    float* gmax     = ws + 34848;    // 32
    float* pcdf     = ws + 34880;    // 2048

    k_stats<<<NIMG * 32, 256,  0, stream>>>(x, blocksum, pmin, pmax);
    k_hist <<<NIMG,      256,  0, stream>>>(pmin, pmax, blocksum, gmin, gmax, pcdf);
    k_apply<<<512,       1024, 0, stream>>>(x, gmin, gmax, pcdf,
                                            w1, b1, w2, b2, w3, b3, alpha, out);
}